// Round 1
// baseline (56.522 us; speedup 1.0000x reference)
//
#include <hip/hip_runtime.h>
#include <math.h>

// Problem constants (fixed by reference setup_inputs)
constexpr int B = 64;
constexpr int S = 1024;
constexpr int D = 256;
constexpr int NNEG = 32;
constexpr int CH = 16;            // chunks per chain in K1
constexpr int ROWS = S / CH;      // 64 rows per block
constexpr int NPAIR = B * (B - 1) / 2;  // 2016
#define EPSN 1e-8f

// ---------------- K1: normalize rows, partial chain sums + raw sums ----------------
// grid = B*CH blocks, 256 threads (4 waves). Each wave handles rows r = wave, wave+4, ...
// Lane l owns dims [4l, 4l+4): one float4 per row -> 1KB coalesced per wave-row.
__global__ __launch_bounds__(256) void k1_partial(const float* __restrict__ x,
                                                  float* __restrict__ pchain,
                                                  float* __restrict__ pp) {
    const int blk  = blockIdx.x;          // 0 .. B*CH-1
    const int b    = blk / CH;
    const int c    = blk % CH;
    const int wave = threadIdx.x >> 6;
    const int lane = threadIdx.x & 63;

    const float* base = x + ((size_t)(b * S + c * ROWS)) * D + lane * 4;

    float4 acc = make_float4(0.f, 0.f, 0.f, 0.f);
    float  ps  = 0.f;

    for (int r = wave; r < ROWS; r += 4) {
        const float4 v = *(const float4*)(base + (size_t)r * D);
        float ss = v.x * v.x + v.y * v.y + v.z * v.z + v.w * v.w;
        #pragma unroll
        for (int m = 1; m < 64; m <<= 1) ss += __shfl_xor(ss, m, 64);
        const float inv = 1.0f / fmaxf(sqrtf(ss), EPSN);
        acc.x += v.x * inv;
        acc.y += v.y * inv;
        acc.z += v.z * inv;
        acc.w += v.w * inv;
        ps += v.x + v.y + v.z + v.w;
    }

    // reduce raw sum across lanes of this wave
    #pragma unroll
    for (int m = 1; m < 64; m <<= 1) ps += __shfl_xor(ps, m, 64);

    __shared__ float4 sacc[4][64];
    __shared__ float  sps[4];
    sacc[wave][lane] = acc;
    if (lane == 0) sps[wave] = ps;
    __syncthreads();

    if (wave == 0) {
        const float4 t0 = sacc[0][lane];
        const float4 t1 = sacc[1][lane];
        const float4 t2 = sacc[2][lane];
        const float4 t3 = sacc[3][lane];
        float4 o;
        o.x = t0.x + t1.x + t2.x + t3.x;
        o.y = t0.y + t1.y + t2.y + t3.y;
        o.z = t0.z + t1.z + t2.z + t3.z;
        o.w = t0.w + t1.w + t2.w + t3.w;
        *(float4*)(pchain + (size_t)blk * D + lane * 4) = o;
        if (lane == 0) pp[blk] = sps[0] + sps[1] + sps[2] + sps[3];
    }
}

// ---------------- K2: reduce chunk partials -> chain_sum, sumsq, pmean ----------------
// grid = B blocks, 256 threads (thread = dim d)
__global__ __launch_bounds__(256) void k2_reduce(const float* __restrict__ pchain,
                                                 const float* __restrict__ pp,
                                                 float* __restrict__ cs,
                                                 float* __restrict__ sq,
                                                 float* __restrict__ pm) {
    const int b = blockIdx.x;
    const int d = threadIdx.x;
    const int wave = d >> 6, lane = d & 63;

    float v = 0.f;
    #pragma unroll
    for (int c = 0; c < CH; ++c) v += pchain[(size_t)(b * CH + c) * D + d];
    cs[b * D + d] = v;

    float s2 = v * v;
    #pragma unroll
    for (int m = 1; m < 64; m <<= 1) s2 += __shfl_xor(s2, m, 64);

    __shared__ float red[4];
    if (lane == 0) red[wave] = s2;
    __syncthreads();
    if (d == 0) {
        sq[b] = red[0] + red[1] + red[2] + red[3];
        float s = 0.f;
        #pragma unroll
        for (int c = 0; c < CH; ++c) s += pp[b * CH + c];
        pm[b] = s / (float)(S * D);
    }
}

// ---------------- K3: finalize all four losses (single block) ----------------
__device__ __forceinline__ float block_sum256(float v, volatile float* red,
                                              int wave, int lane) {
    #pragma unroll
    for (int m = 1; m < 64; m <<= 1) v += __shfl_xor(v, m, 64);
    if (lane == 0) red[wave] = v;
    __syncthreads();
    v = red[0] + red[1] + red[2] + red[3];
    __syncthreads();
    return v;
}

__global__ __launch_bounds__(256) void k3_final(const float* __restrict__ cs,
                                                const float* __restrict__ sq,
                                                const float* __restrict__ pm,
                                                const float* __restrict__ neg,
                                                float* __restrict__ out) {
    constexpr int DP = D + 4;  // pad: row stride 260 -> bank = (4i + d) % 32 varies with i
    __shared__ float lcs[B][DP];          // ~66.6 KB (gfx950 LDS = 160 KB/CU)
    __shared__ float lsq[B], lpm[B], lnn[NNEG];
    __shared__ float nn8[NNEG][8];
    __shared__ float red[4];

    const int t = threadIdx.x;
    const int wave = t >> 6, lane = t & 63;

    // stage chain sums into LDS (float4, DP%4==0 keeps 16B alignment)
    for (int idx = t; idx < B * (D / 4); idx += 256) {
        const int b  = idx / (D / 4);
        const int d4 = idx % (D / 4);
        const float4 v = *(const float4*)(cs + (size_t)b * D + d4 * 4);
        *(float4*)&lcs[b][d4 * 4] = v;
    }
    if (t < B) { lsq[t] = sq[t]; lpm[t] = pm[t]; }

    // hard-negative row partial means: thread -> (k = t/8, part = t%8)
    {
        const int k = t >> 3, part = t & 7;
        float s = 0.f;
        #pragma unroll 8
        for (int e = 0; e < 32; ++e) s += neg[k * 256 + part * 32 + e];
        nn8[k][part] = s;
    }
    __syncthreads();

    if (t < NNEG) {
        float s = 0.f;
        #pragma unroll
        for (int e = 0; e < 8; ++e) s += nn8[t][e];
        lnn[t] = s / (float)D;
    }

    // intra partial (uses lsq, ready)
    float my_intra = 0.f;
    if (t < B) {
        const float ia = (lsq[t] - (float)S) / ((float)S * (float)(S - 1));
        my_intra = fminf(ia, 1.0f);
    }

    // inter: pair dots from LDS
    float my_inter = 0.f;
    const float invS2 = 1.0f / ((float)S * (float)S);
    for (int k = t; k < B * B; k += 256) {
        const int i = k >> 6, j = k & 63;
        if (i < j) {
            float dot = 0.f;
            #pragma unroll 4
            for (int d4 = 0; d4 < D / 4; ++d4) {
                const float4 a  = *(const float4*)&lcs[i][d4 * 4];
                const float4 bb = *(const float4*)&lcs[j][d4 * 4];
                dot += a.x * bb.x + a.y * bb.y + a.z * bb.z + a.w * bb.w;
            }
            my_inter += fminf(dot * invS2, 1.0f);
        }
    }
    __syncthreads();  // lnn ready for everyone

    // hard: mean over (b, k) of relu(n[k] - p[b] + 1)
    float my_hard = 0.f;
    for (int k = t; k < B * NNEG; k += 256) {
        const int bb = k >> 5, nk = k & 31;
        my_hard += fmaxf(lnn[nk] - lpm[bb] + 1.0f, 0.f);
    }

    const float intra = block_sum256(my_intra, red, wave, lane) / (float)B;
    const float inter = block_sum256(my_inter, red, wave, lane) / (float)NPAIR;
    const float hard  = block_sum256(my_hard,  red, wave, lane) / (float)(B * NNEG);

    if (t == 0) {
        out[0] = intra;
        out[1] = inter;
        out[2] = hard;
        out[3] = intra + inter + 0.1f * hard;
    }
}

extern "C" void kernel_launch(void* const* d_in, const int* in_sizes, int n_in,
                              void* d_out, int out_size, void* d_ws, size_t ws_size,
                              hipStream_t stream) {
    const float* x   = (const float*)d_in[0];   // [B, S, D]
    const float* neg = (const float*)d_in[1];   // [NNEG, D]
    float* out = (float*)d_out;

    // workspace layout (floats)
    float* w = (float*)d_ws;
    float* pchain = w;                          // B*CH * D = 262144
    float* pp     = pchain + (size_t)B * CH * D;  // B*CH  = 1024
    float* cs     = pp + B * CH;                // B*D   = 16384
    float* sq     = cs + B * D;                 // B
    float* pm     = sq + B;                     // B

    k1_partial<<<B * CH, 256, 0, stream>>>(x, pchain, pp);
    k2_reduce<<<B, 256, 0, stream>>>(pchain, pp, cs, sq, pm);
    k3_final<<<1, 256, 0, stream>>>(cs, sq, pm, neg, out);
}

// Round 2
// 31.079 us; speedup vs baseline: 1.8187x; 1.8187x over previous
//
#include <hip/hip_runtime.h>
#include <math.h>

// Problem constants (fixed by reference setup_inputs)
constexpr int B = 64;
constexpr int S = 1024;
constexpr int D = 256;
constexpr int NNEG = 32;
constexpr int CH = 16;            // chunks per chain in K1
constexpr int ROWS = S / CH;      // 64 rows per block
constexpr int NPAIR = B * (B - 1) / 2;  // 2016
constexpr int NCELL = B * B;            // 4096 gram cells (i<j live)
#define EPSN 1e-8f

// ---------------- K1: normalize rows, partial chain sums + raw sums ----------------
// grid = B*CH blocks, 256 threads (4 waves). Each wave handles rows r = wave, wave+4, ...
// Lane l owns dims [4l, 4l+4): one float4 per row -> 1KB coalesced per wave-row.
__global__ __launch_bounds__(256) void k1_partial(const float* __restrict__ x,
                                                  float* __restrict__ pchain,
                                                  float* __restrict__ pp) {
    const int blk  = blockIdx.x;          // 0 .. B*CH-1
    const int b    = blk / CH;
    const int c    = blk % CH;
    const int wave = threadIdx.x >> 6;
    const int lane = threadIdx.x & 63;

    const float* base = x + ((size_t)(b * S + c * ROWS)) * D + lane * 4;

    float4 acc = make_float4(0.f, 0.f, 0.f, 0.f);
    float  ps  = 0.f;

    for (int r = wave; r < ROWS; r += 4) {
        const float4 v = *(const float4*)(base + (size_t)r * D);
        float ss = v.x * v.x + v.y * v.y + v.z * v.z + v.w * v.w;
        #pragma unroll
        for (int m = 1; m < 64; m <<= 1) ss += __shfl_xor(ss, m, 64);
        const float inv = 1.0f / fmaxf(sqrtf(ss), EPSN);
        acc.x += v.x * inv;
        acc.y += v.y * inv;
        acc.z += v.z * inv;
        acc.w += v.w * inv;
        ps += v.x + v.y + v.z + v.w;
    }

    // reduce raw sum across lanes of this wave
    #pragma unroll
    for (int m = 1; m < 64; m <<= 1) ps += __shfl_xor(ps, m, 64);

    __shared__ float4 sacc[4][64];
    __shared__ float  sps[4];
    sacc[wave][lane] = acc;
    if (lane == 0) sps[wave] = ps;
    __syncthreads();

    if (wave == 0) {
        const float4 t0 = sacc[0][lane];
        const float4 t1 = sacc[1][lane];
        const float4 t2 = sacc[2][lane];
        const float4 t3 = sacc[3][lane];
        float4 o;
        o.x = t0.x + t1.x + t2.x + t3.x;
        o.y = t0.y + t1.y + t2.y + t3.y;
        o.z = t0.z + t1.z + t2.z + t3.z;
        o.w = t0.w + t1.w + t2.w + t3.w;
        *(float4*)(pchain + (size_t)blk * D + lane * 4) = o;
        if (lane == 0) pp[blk] = sps[0] + sps[1] + sps[2] + sps[3];
    }
}

// ---------------- K2: reduce chunk partials -> chain_sum, sumsq, pmean ----------------
// grid = B blocks, 256 threads (thread = dim d)
__global__ __launch_bounds__(256) void k2_reduce(const float* __restrict__ pchain,
                                                 const float* __restrict__ pp,
                                                 float* __restrict__ cs,
                                                 float* __restrict__ sq,
                                                 float* __restrict__ pm) {
    const int b = blockIdx.x;
    const int d = threadIdx.x;
    const int wave = d >> 6, lane = d & 63;

    float v = 0.f;
    #pragma unroll
    for (int c = 0; c < CH; ++c) v += pchain[(size_t)(b * CH + c) * D + d];
    cs[b * D + d] = v;

    float s2 = v * v;
    #pragma unroll
    for (int m = 1; m < 64; m <<= 1) s2 += __shfl_xor(s2, m, 64);

    __shared__ float red[4];
    if (lane == 0) red[wave] = s2;
    __syncthreads();
    if (d == 0) {
        sq[b] = red[0] + red[1] + red[2] + red[3];
        float s = 0.f;
        #pragma unroll
        for (int c = 0; c < CH; ++c) s += pp[b * CH + c];
        pm[b] = s / (float)(S * D);
    }
}

// ---------------- K3: gram pair dots, one wave per (i,j) cell ----------------
// grid = NCELL/4 = 1024 blocks x 256 threads. cs is 64KB -> L2-resident.
__global__ __launch_bounds__(256) void k3_pairs(const float* __restrict__ cs,
                                                float* __restrict__ pairval) {
    const int wid  = (blockIdx.x * 256 + threadIdx.x) >> 6;  // 0..NCELL-1
    const int lane = threadIdx.x & 63;
    const int i = wid >> 6, j = wid & 63;

    float v = 0.f;
    if (i < j) {
        const float4 a  = *(const float4*)(cs + (size_t)i * D + lane * 4);
        const float4 bb = *(const float4*)(cs + (size_t)j * D + lane * 4);
        float dot = a.x * bb.x + a.y * bb.y + a.z * bb.z + a.w * bb.w;
        #pragma unroll
        for (int m = 1; m < 64; m <<= 1) dot += __shfl_xor(dot, m, 64);
        const float invS2 = 1.0f / ((float)S * (float)S);
        v = fminf(dot * invS2, 1.0f);
    }
    if (lane == 0) pairval[wid] = v;   // 0 for i>=j cells
}

// ---------------- K4: finalize all four losses (single small block) ----------------
__device__ __forceinline__ float block_sum256(float v, volatile float* red,
                                              int wave, int lane) {
    #pragma unroll
    for (int m = 1; m < 64; m <<= 1) v += __shfl_xor(v, m, 64);
    if (lane == 0) red[wave] = v;
    __syncthreads();
    v = red[0] + red[1] + red[2] + red[3];
    __syncthreads();
    return v;
}

__global__ __launch_bounds__(256) void k4_final(const float* __restrict__ pairval,
                                                const float* __restrict__ sq,
                                                const float* __restrict__ pm,
                                                const float* __restrict__ neg,
                                                float* __restrict__ out) {
    __shared__ float lnn[NNEG];
    __shared__ float nn8[NNEG][8];
    __shared__ float red[4];

    const int t = threadIdx.x;
    const int wave = t >> 6, lane = t & 63;

    // hard-negative row partial means: thread -> (k = t/8, part = t%8)
    {
        const int k = t >> 3, part = t & 7;
        float s = 0.f;
        #pragma unroll 8
        for (int e = 0; e < 32; ++e) s += neg[k * 256 + part * 32 + e];
        nn8[k][part] = s;
    }
    __syncthreads();
    if (t < NNEG) {
        float s = 0.f;
        #pragma unroll
        for (int e = 0; e < 8; ++e) s += nn8[t][e];
        lnn[t] = s / (float)D;
    }

    // inter: sum the 4096 gram-cell values (i>=j cells are 0)
    float my_inter = 0.f;
    for (int k = t; k < NCELL; k += 256) my_inter += pairval[k];

    // intra from closed form
    float my_intra = 0.f;
    if (t < B) {
        const float ia = (sq[t] - (float)S) / ((float)S * (float)(S - 1));
        my_intra = fminf(ia, 1.0f);
    }
    __syncthreads();  // lnn ready

    // hard: mean over (b, k) of relu(n[k] - p[b] + 1)
    float my_hard = 0.f;
    for (int k = t; k < B * NNEG; k += 256) {
        const int bb = k >> 5, nk = k & 31;
        my_hard += fmaxf(lnn[nk] - pm[bb] + 1.0f, 0.f);
    }

    const float intra = block_sum256(my_intra, red, wave, lane) / (float)B;
    const float inter = block_sum256(my_inter, red, wave, lane) / (float)NPAIR;
    const float hard  = block_sum256(my_hard,  red, wave, lane) / (float)(B * NNEG);

    if (t == 0) {
        out[0] = intra;
        out[1] = inter;
        out[2] = hard;
        out[3] = intra + inter + 0.1f * hard;
    }
}

extern "C" void kernel_launch(void* const* d_in, const int* in_sizes, int n_in,
                              void* d_out, int out_size, void* d_ws, size_t ws_size,
                              hipStream_t stream) {
    const float* x   = (const float*)d_in[0];   // [B, S, D]
    const float* neg = (const float*)d_in[1];   // [NNEG, D]
    float* out = (float*)d_out;

    // workspace layout (floats)
    float* w = (float*)d_ws;
    float* pchain  = w;                              // B*CH*D = 262144
    float* pp      = pchain + (size_t)B * CH * D;    // B*CH   = 1024
    float* cs      = pp + B * CH;                    // B*D    = 16384
    float* sq      = cs + B * D;                     // B
    float* pm      = sq + B;                         // B
    float* pairval = pm + B;                         // NCELL  = 4096

    k1_partial<<<B * CH, 256, 0, stream>>>(x, pchain, pp);
    k2_reduce<<<B, 256, 0, stream>>>(pchain, pp, cs, sq, pm);
    k3_pairs<<<NCELL / 4, 256, 0, stream>>>(cs, pairval);
    k4_final<<<1, 256, 0, stream>>>(pairval, sq, pm, neg, out);
}